// Round 9
// baseline (60.491 us; speedup 1.0000x reference)
//
#include <hip/hip_runtime.h>
#include <math.h>

#define FAR_DELTA 1e10f

// 4 rays per wave: lanes 0-31 = even ray, 32-63 = odd ray, of TWO pairs
// (rays 4q..4q+3). All 10 float4 loads are issued before any wait (depth/
// density first, features last) so ~10KB/wave is in flight and the scan
// hides the feature-load latency. Two independent compute chains (pair A,
// pair B) interleave for ILP. Transmittance in exclusive form:
// w_j = E_j - E_{j+1}, E_j = exp(-cum_j) -> 5 INDEPENDENT exps after a
// 3-add chain (vs 9-deep serial product). FAR sample: E_4 = exp(-1e9) = 0.
__global__ __launch_bounds__(256, 8) void volrend_kernel(
    const float* __restrict__ density,   // (B,128,1) f32
    const float* __restrict__ feature,   // (B,128,3) f32
    const float* __restrict__ depth,     // (B,128)   f32
    float* __restrict__ feat_out,        // (B,3) f32
    float* __restrict__ depth_out,       // (B,1) f32
    int B)
{
    const int lane = threadIdx.x & 63;
    const int li   = lane & 31;          // lane within half-wave
    const int half = lane >> 5;          // 0 = even ray, 1 = odd ray
    const int widb = threadIdx.x >> 6;
    const int wpb  = blockDim.x >> 6;
    const int q    = blockIdx.x * wpb + widb;   // quad of rays per wave
    const int nquad = B >> 2;
    if (q >= nquad) return;

    const int rayA = q * 4 + half;
    const int rayB = q * 4 + 2 + half;
    const size_t baseA = (size_t)rayA * 128 + (size_t)li * 4;
    const size_t baseB = (size_t)rayB * 128 + (size_t)li * 4;

    // issue all loads up front; scan needs only zv/dv (vmcnt leaves features in flight)
    float4 zvA = *reinterpret_cast<const float4*>(depth   + baseA);
    float4 dvA = *reinterpret_cast<const float4*>(density + baseA);
    float4 zvB = *reinterpret_cast<const float4*>(depth   + baseB);
    float4 dvB = *reinterpret_cast<const float4*>(density + baseB);
    const float4* fpA = reinterpret_cast<const float4*>(feature + baseA * 3);
    const float4* fpB = reinterpret_cast<const float4*>(feature + baseB * 3);
    float4 fA0 = fpA[0], fA1 = fpA[1], fA2 = fpA[2];
    float4 fB0 = fpB[0], fB1 = fpB[1], fB2 = fpB[2];

    // ---- pair A and pair B chains, interleaved by the compiler ----
    float znA = __shfl_down(zvA.x, 1);
    float znB = __shfl_down(zvB.x, 1);

    float a0 = dvA.x * (zvA.y - zvA.x);
    float a1 = dvA.y * (zvA.z - zvA.y);
    float a2 = dvA.z * (zvA.w - zvA.z);
    float a3 = dvA.w * ((li == 31) ? FAR_DELTA : (znA - zvA.w));
    float b0 = dvB.x * (zvB.y - zvB.x);
    float b1 = dvB.y * (zvB.z - zvB.y);
    float b2 = dvB.z * (zvB.w - zvB.z);
    float b3 = dvB.w * ((li == 31) ? FAR_DELTA : (znB - zvB.w));

    float lsumA = a0 + a1 + a2 + ((li == 31) ? 0.0f : a3);
    float lsumB = b0 + b1 + b2 + ((li == 31) ? 0.0f : b3);

    float sA = lsumA, sB = lsumB;
    #pragma unroll
    for (int off = 1; off < 32; off <<= 1) {
        float nA = __shfl_up(sA, off);
        float nB = __shfl_up(sB, off);
        if (li >= off) { sA += nA; sB += nB; }
    }
    float cA0 = sA - lsumA;              // exclusive prefix for sample 4*li
    float cB0 = sB - lsumB;

    float cA1 = cA0 + a0, cA2 = cA1 + a1, cA3 = cA2 + a2;
    float cB1 = cB0 + b0, cB2 = cB1 + b1, cB3 = cB2 + b2;

    // independent exps; E4 = 0 for the FAR sample, = E3 when density==0
    float EA0 = __expf(-cA0), EA1 = __expf(-cA1), EA2 = __expf(-cA2),
          EA3 = __expf(-cA3), EA4 = __expf(-(cA3 + a3));
    float EB0 = __expf(-cB0), EB1 = __expf(-cB1), EB2 = __expf(-cB2),
          EB3 = __expf(-cB3), EB4 = __expf(-(cB3 + b3));

    float wA0 = EA0 - EA1, wA1 = EA1 - EA2, wA2 = EA2 - EA3, wA3 = EA3 - EA4;
    float wB0 = EB0 - EB1, wB1 = EB1 - EB2, wB2 = EB2 - EB3, wB3 = EB3 - EB4;

    float rA = wA0 * fA0.x + wA1 * fA0.w + wA2 * fA1.z + wA3 * fA2.y;
    float gA = wA0 * fA0.y + wA1 * fA1.x + wA2 * fA1.w + wA3 * fA2.z;
    float bA = wA0 * fA0.z + wA1 * fA1.y + wA2 * fA2.x + wA3 * fA2.w;
    float dA = wA0 * zvA.x + wA1 * zvA.y + wA2 * zvA.z + wA3 * zvA.w;
    float rB = wB0 * fB0.x + wB1 * fB0.w + wB2 * fB1.z + wB3 * fB2.y;
    float gB = wB0 * fB0.y + wB1 * fB1.x + wB2 * fB1.w + wB3 * fB2.z;
    float bB = wB0 * fB0.z + wB1 * fB1.y + wB2 * fB2.x + wB3 * fB2.w;
    float dB = wB0 * zvB.x + wB1 * zvB.y + wB2 * zvB.z + wB3 * zvB.w;

    // butterfly over each 32-lane half; 8 independent chains interleave
    #pragma unroll
    for (int off = 16; off >= 1; off >>= 1) {
        rA += __shfl_xor(rA, off);  gA += __shfl_xor(gA, off);
        bA += __shfl_xor(bA, off);  dA += __shfl_xor(dA, off);
        rB += __shfl_xor(rB, off);  gB += __shfl_xor(gB, off);
        bB += __shfl_xor(bB, off);  dB += __shfl_xor(dB, off);
    }

    if (li == 0) {                       // lanes 0 and 32: write both rays
        feat_out[(size_t)rayA * 3 + 0] = rA;
        feat_out[(size_t)rayA * 3 + 1] = gA;
        feat_out[(size_t)rayA * 3 + 2] = bA;
        depth_out[rayA] = dA;
        feat_out[(size_t)rayB * 3 + 0] = rB;
        feat_out[(size_t)rayB * 3 + 1] = gB;
        feat_out[(size_t)rayB * 3 + 2] = bB;
        depth_out[rayB] = dB;
    }
}

extern "C" void kernel_launch(void* const* d_in, const int* in_sizes, int n_in,
                              void* d_out, int out_size, void* d_ws, size_t ws_size,
                              hipStream_t stream) {
    const float* density = (const float*)d_in[0];
    const float* feature = (const float*)d_in[1];
    const float* depth   = (const float*)d_in[2];
    const int N = 128;
    const int B = in_sizes[2] / N;                 // depth_values is (B,N)

    float* feat_out  = (float*)d_out;              // (B,3) flat f32
    float* depth_out = feat_out + (size_t)B * 3;   // (B,1) flat f32

    const int nquad = B >> 2;                      // 32768 (4 rays per wave)
    const int wavesPerBlock = 4;                   // 256 threads
    dim3 block(256);
    dim3 grid((nquad + wavesPerBlock - 1) / wavesPerBlock);  // 8192 blocks
    hipLaunchKernelGGL(volrend_kernel, grid, block, 0, stream,
                       density, feature, depth, feat_out, depth_out, B);
}